// Round 13
// baseline (275.308 us; speedup 1.0000x reference)
//
#include <hip/hip_runtime.h>
#include <hip/hip_bf16.h>
#include <cstdint>
#include <cstddef>

typedef unsigned short u16;
typedef short bf16x8 __attribute__((ext_vector_type(8)));
typedef float f32x4 __attribute__((ext_vector_type(4)));

constexpr int Ns = 512;   // N
constexpr int Dd = 128;   // D
constexpr int Cc = 128;   // C
#define EPSV 1e-5f

__device__ __forceinline__ u16 f2bf(float f){
    __hip_bfloat16 h = __float2bfloat16(f);
    return *reinterpret_cast<u16*>(&h);
}
__device__ __forceinline__ float bf2f(u16 h){
    return __uint_as_float(((uint32_t)h) << 16);
}
__device__ __forceinline__ float sigmoidf_(float x){
    return __builtin_amdgcn_rcpf(1.0f + __expf(-x));   // ~1ulp, fine at bf16
}

// same-wave LDS write->read ordering fence (guide rule #18)
#define LDS_FENCE do {                                         \
    asm volatile("s_waitcnt lgkmcnt(0)" ::: "memory");         \
    __builtin_amdgcn_sched_barrier(0);                         \
} while (0)

// ---------------------------------------------------------------------------
// K0: weights -> bf16, transposed [n][k].  Order: Wl,Wlg,Wr,Wrg,Wog,Wo
// ---------------------------------------------------------------------------
__global__ void k_prep(const float* __restrict__ Wl, const float* __restrict__ Wlg,
                       const float* __restrict__ Wr, const float* __restrict__ Wrg,
                       const float* __restrict__ Wog, const float* __restrict__ Wo,
                       u16* __restrict__ Wt){
    int idx = blockIdx.x * 256 + threadIdx.x;
    if (idx >= 6 * 16384) return;
    int m = idx >> 14; int nk = idx & 16383; int n = nk >> 7; int k = nk & 127;
    const float* W = (m == 0) ? Wl : (m == 1) ? Wlg : (m == 2) ? Wr
                   : (m == 3) ? Wrg : (m == 4) ? Wog : Wo;
    Wt[idx] = f2bf(W[k * Cc + n]);
}

// ---------------------------------------------------------------------------
// K1: LN(x) -> xn (stored bf16, natural [a][b][d]) + 4 GEMMs (L/R pairs).
// R11-verified structure (119 us); xn register stores replace the og phase
// entirely (og = sigmoid(xn@Wog+bog) is now computed in k3 from xn).
// ---------------------------------------------------------------------------
__global__ __launch_bounds__(256) void k1(
    const float* __restrict__ x, const float* __restrict__ g_ln, const float* __restrict__ b_ln,
    const u16* __restrict__ Wt,
    const float* __restrict__ bl, const float* __restrict__ blg,
    const float* __restrict__ br, const float* __restrict__ brg,
    u16* __restrict__ left, u16* __restrict__ right, u16* __restrict__ xn)
{
    __shared__ u16  SB[8704];          // aliased: xn tile [64][136] / wp-stage [4][32][68]
    __shared__ float gln[128], bln[128];

    const int t   = threadIdx.x;
    const int bid = blockIdx.x;
    const int a0  = (bid >> 6) << 3;
    const int b0  = (bid & 63) << 3;
    const int w = t >> 6, l = t & 63;
    const int lrow = l & 15, g = l >> 4;
    const int nb = w * 32;
    const int orow = g << 2;
    const int kb = a0 >> 3;

    // ---- prologue: x loads, LN stats, normalize into SB + global xn ----
    const int r = t >> 2, q = t & 3;
    const int aa = a0 + (r & 7), bb = b0 + (r >> 3);
    const float4* xrow = reinterpret_cast<const float4*>(x + ((size_t)aa * Ns + bb) * Dd);
    u16* xnrow = xn + ((size_t)aa * Ns + bb) * Dd;
    float4 xv[8];
#pragma unroll
    for (int i2 = 0; i2 < 8; ++i2) xv[i2] = xrow[q + 4 * i2];
    if (t < 128){ gln[t] = g_ln[t]; bln[t] = b_ln[t]; }

    float s1 = 0.f, s2 = 0.f;
#pragma unroll
    for (int i2 = 0; i2 < 8; ++i2){
        float4 v = xv[i2];
        s1 += v.x + v.y + v.z + v.w;
        s2 += v.x * v.x + v.y * v.y + v.z * v.z + v.w * v.w;
    }
    s1 += __shfl_xor(s1, 1); s1 += __shfl_xor(s1, 2);
    s2 += __shfl_xor(s2, 1); s2 += __shfl_xor(s2, 2);
    const float mm  = s1 * (1.0f / 128.0f);
    const float rsv = rsqrtf(s2 * (1.0f / 128.0f) - mm * mm + EPSV);
    __syncthreads();                   // (1) gln/bln ready
#pragma unroll
    for (int i2 = 0; i2 < 8; ++i2){
        const int d = (q + 4 * i2) * 4;
        ushort4 o;
        o.x = f2bf((xv[i2].x - mm) * rsv * gln[d + 0] + bln[d + 0]);
        o.y = f2bf((xv[i2].y - mm) * rsv * gln[d + 1] + bln[d + 1]);
        o.z = f2bf((xv[i2].z - mm) * rsv * gln[d + 2] + bln[d + 2]);
        o.w = f2bf((xv[i2].w - mm) * rsv * gln[d + 3] + bln[d + 3]);
        *reinterpret_cast<ushort4*>(&SB[r * 136 + d]) = o;
        *reinterpret_cast<ushort4*>(xnrow + d) = o;      // fire-and-forget xn store
    }
    __syncthreads();                   // (2) xn tile ready

    // ---- A-fragments once (R4-verified) ----
    bf16x8 af[4][4];
#pragma unroll
    for (int ks = 0; ks < 4; ++ks)
#pragma unroll
        for (int rf = 0; rf < 4; ++rf)
            af[ks][rf] = *reinterpret_cast<const bf16x8*>(&SB[(rf * 16 + lrow) * 136 + ks * 32 + g * 8]);
    __syncthreads();                   // (3) all af reads done; SB free

    u16* SBw = &SB[w * 32 * 68];       // wave-private staging (32 cols x 68)
    const f32x4 zero4 = {0.f, 0.f, 0.f, 0.f};
    f32x4 aV[4], aG[4];

    auto GEMM1 = [&](const u16* WV, const u16* WG, int cf){
        const int col = nb + cf * 16 + lrow;
#pragma unroll
        for (int rf = 0; rf < 4; ++rf){ aV[rf] = zero4; aG[rf] = zero4; }
#pragma unroll
        for (int ks = 0; ks < 4; ++ks){
            bf16x8 bv = *reinterpret_cast<const bf16x8*>(WV + (size_t)col * 128 + ks * 32 + g * 8);
            bf16x8 bg = *reinterpret_cast<const bf16x8*>(WG + (size_t)col * 128 + ks * 32 + g * 8);
#pragma unroll
            for (int rf = 0; rf < 4; ++rf)
                aV[rf] = __builtin_amdgcn_mfma_f32_16x16x32_bf16(af[ks][rf], bv, aV[rf], 0, 0, 0);
#pragma unroll
            for (int rf = 0; rf < 4; ++rf)
                aG[rf] = __builtin_amdgcn_mfma_f32_16x16x32_bf16(af[ks][rf], bg, aG[rf], 0, 0, 0);
        }
    };
    auto STW = [&](const float* bV, const float* bG, int cf){
        const int cl2 = cf * 16 + lrow;
        const int col = nb + cl2;
        const float bVv = bV[col], bGv = bG[col];
#pragma unroll
        for (int rf = 0; rf < 4; ++rf){
            ushort4 pk;
#pragma unroll
            for (int j = 0; j < 4; ++j){
                const float vv = aV[rf][j] + bVv;
                const float gg = aG[rf][j] + bGv;
                ((u16*)&pk)[j] = f2bf(sigmoidf_(gg) * vv);
            }
            *reinterpret_cast<ushort4*>(&SBw[cl2 * 68 + rf * 16 + orow]) = pk;
        }
    };
    auto STORE = [&](u16* dst){
#pragma unroll
        for (int it = 0; it < 4; ++it){
            const int cl2 = it * 8 + (l >> 3);
            const int s   = l & 7;
            int4 v = *reinterpret_cast<const int4*>(&SBw[cl2 * 68 + s * 8]);
            *reinterpret_cast<int4*>(dst + (((size_t)(nb + cl2) * 64 + kb) * Ns + b0) * 8 + s * 8) = v;
        }
    };

    // ---- barrier-free L/R pipeline (per-wave; fences order same-wave LDS reuse) ----
    GEMM1(Wt,             Wt + 16384,     0); STW(bl, blg, 0);
    GEMM1(Wt,             Wt + 16384,     1); STW(bl, blg, 1);
    LDS_FENCE;
    STORE(left);
    LDS_FENCE;
    GEMM1(Wt + 2 * 16384, Wt + 3 * 16384, 0); STW(br, brg, 0);
    GEMM1(Wt + 2 * 16384, Wt + 3 * 16384, 1); STW(br, brg, 1);
    LDS_FENCE;
    STORE(right);
}

// ---------------------------------------------------------------------------
// K2: om[c][i][j] = sum_k left[c][k][i] * right[c][k][j]   (per-channel GEMM)
// 1-D grid 2048, XCD-swizzled so each XCD owns 16 whole channels.  (frozen)
// ---------------------------------------------------------------------------
#define K2_LOAD(AF, BF, KS) do {                                                    \
    const size_t kbrow_ = (size_t)((KS) * 4 + lkb) * Ns;                            \
    _Pragma("unroll") for (int rf = 0; rf < 4; ++rf)                                \
        AF[rf] = *reinterpret_cast<const bf16x8*>(Lc + (kbrow_ + ib + rf * 16 + lrow) * 8); \
    _Pragma("unroll") for (int cf = 0; cf < 4; ++cf)                                \
        BF[cf] = *reinterpret_cast<const bf16x8*>(Rc + (kbrow_ + jb + cf * 16 + lrow) * 8); \
} while (0)

#define K2_MM(AF, BF) do {                                                          \
    _Pragma("unroll") for (int rf = 0; rf < 4; ++rf)                                \
    _Pragma("unroll") for (int cf = 0; cf < 4; ++cf)                                \
        acc[rf][cf] = __builtin_amdgcn_mfma_f32_16x16x32_bf16(AF[rf], BF[cf], acc[rf][cf], 0, 0, 0); \
} while (0)

__global__ __launch_bounds__(256) void k2(const u16* __restrict__ left,
                                          const u16* __restrict__ right,
                                          u16* __restrict__ om)
{
    __shared__ u16 sO[128][136];
    const int bid = blockIdx.x;
    const int xcd = bid & 7, idxx = bid >> 3;
    const int virt = xcd * 256 + idxx;
    const int c    = virt >> 4;
    const int tile = virt & 15;
    const int iy = tile >> 2, jx = tile & 3;
    const int t = threadIdx.x, w = t >> 6, l = t & 63;
    const int wr = w >> 1, wc = w & 1;
    const int ib = iy * 128 + wr * 64;
    const int jb = jx * 128 + wc * 64;
    const int lrow = l & 15, lkb = l >> 4;
    const u16* Lc = left  + (size_t)c * (Ns * Ns);
    const u16* Rc = right + (size_t)c * (Ns * Ns);
    const f32x4 zero4 = {0.f, 0.f, 0.f, 0.f};
    f32x4 acc[4][4];
#pragma unroll
    for (int rf = 0; rf < 4; ++rf)
#pragma unroll
        for (int cf = 0; cf < 4; ++cf) acc[rf][cf] = zero4;

    bf16x8 a0f[4], b0f[4], a1f[4], b1f[4];
    K2_LOAD(a0f, b0f, 0);
#pragma unroll
    for (int ks = 0; ks < 16; ks += 2){
        K2_LOAD(a1f, b1f, ks + 1);
        K2_MM(a0f, b0f);
        if (ks + 2 < 16) K2_LOAD(a0f, b0f, ks + 2);
        K2_MM(a1f, b1f);
    }

    const int orow = (l >> 4) << 2;
#pragma unroll
    for (int rf = 0; rf < 4; ++rf)
#pragma unroll
        for (int j2 = 0; j2 < 4; ++j2){
            const int rloc = wr * 64 + rf * 16 + orow + j2;
#pragma unroll
            for (int cf = 0; cf < 4; ++cf)
                sO[rloc][wc * 64 + cf * 16 + lrow] = f2bf(acc[rf][cf][j2]);
        }
    __syncthreads();
    u16* obase = om + (size_t)c * Ns * Ns + (size_t)(iy * 128) * Ns + jx * 128;
#pragma unroll
    for (int s = 0; s < 8; ++s){
        const int gg = s * 256 + t;
        const int row = gg >> 4, co = (gg & 15) * 8;
        int4 v = *reinterpret_cast<const int4*>(&sO[row][co]);
        *reinterpret_cast<int4*>(obase + (size_t)row * Ns + co) = v;
    }
}

// ---------------------------------------------------------------------------
// K3: out = sigmoid(xn @ Wog + bog) * (LN_c(om) @ Wo + bo), fp32 out.
// xn read as bf16 (same bytes as the old og read); dual GEMM (R11-verified
// pattern); og never materialized.
// ---------------------------------------------------------------------------
__global__ __launch_bounds__(256) void k3(
    const u16* __restrict__ om, const u16* __restrict__ xn, const u16* __restrict__ Wt,
    const float* __restrict__ g2, const float* __restrict__ b2,
    const float* __restrict__ bogv, const float* __restrict__ bo,
    float* __restrict__ out)
{
    __shared__ char smem[34816];
    u16* X  = reinterpret_cast<u16*>(smem);           // [64][136] om tile -> LN_c
    u16* Xn = reinterpret_cast<u16*>(smem) + 8704;    // [64][136] xn tile
    __shared__ float sg2[128], sb2[128];
    const int i  = blockIdx.y;
    const int j0 = blockIdx.x * 64;
    const int t  = threadIdx.x;
    if (t < 128){ sg2[t] = g2[t]; sb2[t] = b2[t]; }
    {   // om transpose load into X ([c][j] -> [j][c])
        const int c = t >> 1, jh = (t & 1) * 32;
        const u16* src = om + (size_t)c * Ns * Ns + (size_t)i * Ns + j0 + jh;
#pragma unroll
        for (int s = 0; s < 8; ++s){
            ushort4 v = reinterpret_cast<const ushort4*>(src)[s];
            const int jj = jh + s * 4;
            X[(jj + 0) * 136 + c] = v.x; X[(jj + 1) * 136 + c] = v.y;
            X[(jj + 2) * 136 + c] = v.z; X[(jj + 3) * 136 + c] = v.w;
        }
    }
    {   // xn natural load into Xn ([j][d], coalesced int4)
        const int jj = t >> 2, qq = t & 3;
        const u16* src = xn + ((size_t)i * Ns + j0 + jj) * Dd + qq * 32;
#pragma unroll
        for (int s = 0; s < 4; ++s)
            *reinterpret_cast<int4*>(&Xn[jj * 136 + qq * 32 + s * 8]) = reinterpret_cast<const int4*>(src)[s];
    }
    __syncthreads();
    const int r = t >> 2, q = t & 3;
    {   // LN over c on X (in place)
        float a1 = 0.f, a2 = 0.f;
#pragma unroll
        for (int e = 0; e < 32; ++e){
            const float v = bf2f(X[r * 136 + q * 32 + e]);
            a1 += v; a2 += v * v;
        }
        a1 += __shfl_xor(a1, 1); a1 += __shfl_xor(a1, 2);
        a2 += __shfl_xor(a2, 1); a2 += __shfl_xor(a2, 2);
        const float mm  = a1 * (1.0f / 128.0f);
        const float rsv = rsqrtf(a2 * (1.0f / 128.0f) - mm * mm + EPSV);
#pragma unroll
        for (int e = 0; e < 32; ++e){
            const int cc = q * 32 + e;
            const float v = bf2f(X[r * 136 + cc]);
            X[r * 136 + cc] = f2bf((v - mm) * rsv * sg2[cc] + sb2[cc]);
        }
    }
    __syncthreads();

    // ---- dual GEMM: accW = X @ WoT, accO = Xn @ WogT ----
    const int w = t >> 6, l = t & 63;
    const int lrow = l & 15, lk = (l >> 4) << 3, nbv = w * 32, orow = (l >> 4) << 2;
    const u16* WOG = Wt + (size_t)4 * 16384;
    const u16* WO  = Wt + (size_t)5 * 16384;
    const f32x4 zero4 = {0.f, 0.f, 0.f, 0.f};
    f32x4 accW[4][2], accO[4][2];
#pragma unroll
    for (int rf = 0; rf < 4; ++rf)
#pragma unroll
        for (int cf = 0; cf < 2; ++cf){ accW[rf][cf] = zero4; accO[rf][cf] = zero4; }
#pragma unroll
    for (int ks = 0; ks < 4; ++ks){
        const int k0 = ks * 32 + lk;
        bf16x8 af[4], afn[4];
#pragma unroll
        for (int rf = 0; rf < 4; ++rf){
            af[rf]  = *reinterpret_cast<const bf16x8*>(&X[(rf * 16 + lrow) * 136 + k0]);
            afn[rf] = *reinterpret_cast<const bf16x8*>(&Xn[(rf * 16 + lrow) * 136 + k0]);
        }
#pragma unroll
        for (int cf = 0; cf < 2; ++cf){
            const int colg = nbv + cf * 16 + lrow;
            bf16x8 bv = *reinterpret_cast<const bf16x8*>(WO  + (size_t)colg * 128 + k0);
            bf16x8 bg = *reinterpret_cast<const bf16x8*>(WOG + (size_t)colg * 128 + k0);
#pragma unroll
            for (int rf = 0; rf < 4; ++rf)
                accW[rf][cf] = __builtin_amdgcn_mfma_f32_16x16x32_bf16(af[rf], bv, accW[rf][cf], 0, 0, 0);
#pragma unroll
            for (int rf = 0; rf < 4; ++rf)
                accO[rf][cf] = __builtin_amdgcn_mfma_f32_16x16x32_bf16(afn[rf], bg, accO[rf][cf], 0, 0, 0);
        }
    }
    // ---- gate in registers ----
    float gv[2][4][4];
#pragma unroll
    for (int cf = 0; cf < 2; ++cf){
        const int cg = nbv + cf * 16 + lrow;
        const float bov = bo[cg], bogc = bogv[cg];
#pragma unroll
        for (int rf = 0; rf < 4; ++rf)
#pragma unroll
            for (int j = 0; j < 4; ++j)
                gv[cf][rf][j] = sigmoidf_(accO[rf][cf][j] + bogc) * (accW[rf][cf][j] + bov);
    }
    __syncthreads();                      // X/Xn reads done; smem -> sF
    float* sF = reinterpret_cast<float*>(smem);
#pragma unroll
    for (int cf = 0; cf < 2; ++cf){
        const int cg = nbv + cf * 16 + lrow;
#pragma unroll
        for (int rf = 0; rf < 4; ++rf)
#pragma unroll
            for (int j = 0; j < 4; ++j){
                const int row = rf * 16 + orow + j;
                sF[row * 128 + cg] = gv[cf][rf][j];
            }
    }
    __syncthreads();                      // sF ready
    const float4* sF4 = reinterpret_cast<const float4*>(smem);
    float* obase = out + ((size_t)i * Ns + j0) * Cc;
#pragma unroll
    for (int s = 0; s < 8; ++s){
        const int gg = s * 256 + t;
        const int row = gg >> 5, co = (gg & 31) * 4;
        float4 v = sF4[gg];
        *reinterpret_cast<float4*>(obase + (size_t)row * Cc + co) = v;
    }
}

// ---------------------------------------------------------------------------
extern "C" void kernel_launch(void* const* d_in, const int* in_sizes, int n_in,
                              void* d_out, int out_size, void* d_ws, size_t ws_size,
                              hipStream_t stream)
{
    const float* x    = (const float*)d_in[0];
    const float* ling = (const float*)d_in[1];
    const float* linb = (const float*)d_in[2];
    const float* loutg= (const float*)d_in[3];
    const float* loutb= (const float*)d_in[4];
    const float* Wl   = (const float*)d_in[5];
    const float* bl   = (const float*)d_in[6];
    const float* Wr   = (const float*)d_in[7];
    const float* br   = (const float*)d_in[8];
    const float* Wo   = (const float*)d_in[9];
    const float* bo   = (const float*)d_in[10];
    const float* Wlg  = (const float*)d_in[11];
    const float* blg  = (const float*)d_in[12];
    const float* Wrg  = (const float*)d_in[13];
    const float* brg  = (const float*)d_in[14];
    const float* Wog  = (const float*)d_in[15];
    const float* bog  = (const float*)d_in[16];

    char* ws = (char*)d_ws;
    u16* Wt = (u16*)ws;
    const size_t off = 256 * 1024;
    const size_t SZ  = (size_t)33554432 * 2;   // 64 MiB per bf16 tensor
    u16* left  = (u16*)(ws + off);
    u16* right = (u16*)(ws + off + SZ);
    u16* xn    = (u16*)(ws + off + 2 * SZ);
    u16* om    = (u16*)(ws + off + 3 * SZ);

    hipLaunchKernelGGL(k_prep, dim3(384), dim3(256), 0, stream, Wl, Wlg, Wr, Wrg, Wog, Wo, Wt);
    hipLaunchKernelGGL(k1, dim3(4096), dim3(256), 0, stream,
                       x, ling, linb, Wt, bl, blg, br, brg, left, right, xn);
    hipLaunchKernelGGL(k2, dim3(2048), dim3(256), 0, stream, left, right, om);
    hipLaunchKernelGGL(k3, dim3(8, 512), dim3(256), 0, stream,
                       om, xn, Wt, loutg, loutb, bog, bo, (float*)d_out);
}

// Round 14
// 257.679 us; speedup vs baseline: 1.0684x; 1.0684x over previous
//
#include <hip/hip_runtime.h>
#include <hip/hip_bf16.h>
#include <cstdint>
#include <cstddef>

typedef unsigned short u16;
typedef short bf16x8 __attribute__((ext_vector_type(8)));
typedef float f32x4 __attribute__((ext_vector_type(4)));

constexpr int Ns = 512;   // N
constexpr int Dd = 128;   // D
constexpr int Cc = 128;   // C
#define EPSV 1e-5f

__device__ __forceinline__ u16 f2bf(float f){
    __hip_bfloat16 h = __float2bfloat16(f);
    return *reinterpret_cast<u16*>(&h);
}
__device__ __forceinline__ float bf2f(u16 h){
    return __uint_as_float(((uint32_t)h) << 16);
}
__device__ __forceinline__ float sigmoidf_(float x){
    return __builtin_amdgcn_rcpf(1.0f + __expf(-x));   // ~1ulp, fine at bf16
}

// same-wave LDS write->read ordering fence (guide rule #18)
#define LDS_FENCE do {                                         \
    asm volatile("s_waitcnt lgkmcnt(0)" ::: "memory");         \
    __builtin_amdgcn_sched_barrier(0);                         \
} while (0)

// ---------------------------------------------------------------------------
// K0: weights -> bf16, transposed [n][k].  Order: Wl,Wlg,Wr,Wrg,Wog,Wo
// ---------------------------------------------------------------------------
__global__ void k_prep(const float* __restrict__ Wl, const float* __restrict__ Wlg,
                       const float* __restrict__ Wr, const float* __restrict__ Wrg,
                       const float* __restrict__ Wog, const float* __restrict__ Wo,
                       u16* __restrict__ Wt){
    int idx = blockIdx.x * 256 + threadIdx.x;
    if (idx >= 6 * 16384) return;
    int m = idx >> 14; int nk = idx & 16383; int n = nk >> 7; int k = nk & 127;
    const float* W = (m == 0) ? Wl : (m == 1) ? Wlg : (m == 2) ? Wr
                   : (m == 3) ? Wrg : (m == 4) ? Wog : Wo;
    Wt[idx] = f2bf(W[k * Cc + n]);
}

// ---------------------------------------------------------------------------
// K1 (R8 base + occupancy fix): LN(x) then 5 GEMMs.
// xn tile lives in its OWN LDS region (never aliased) -> A-fragments are
// re-read from LDS inside each GEMM group (32 transient regs) instead of
// being held in 64 live registers for the whole kernel.  Unified regs
// ~110 -> target 4 waves/SIMD (was ~170 -> 2-3 waves, 30% occ).
// Staging (wave-private L/R, block-staged og) in a second LDS region.
// ---------------------------------------------------------------------------
__global__ __launch_bounds__(256) void k1(
    const float* __restrict__ x, const float* __restrict__ g_ln, const float* __restrict__ b_ln,
    const u16* __restrict__ Wt,
    const float* __restrict__ bl, const float* __restrict__ blg,
    const float* __restrict__ br, const float* __restrict__ brg,
    const float* __restrict__ bog,
    u16* __restrict__ left, u16* __restrict__ right, u16* __restrict__ og)
{
    __shared__ u16  SB[8704];          // xn [64][136] — persistent, read-only after (2)
    __shared__ u16  SB2[8704];         // wp-stage [4][32][68] / og stage [64][132]
    __shared__ float gln[128], bln[128];

    const int t   = threadIdx.x;
    const int bid = blockIdx.x;
    const int a0  = (bid >> 6) << 3;
    const int b0  = (bid & 63) << 3;
    const int w = t >> 6, l = t & 63;
    const int lrow = l & 15, g = l >> 4;
    const int nb = w * 32;
    const int orow = g << 2;
    const int kb = a0 >> 3;

    // ---- prologue: x loads, LN stats, normalize into SB ----
    const int r = t >> 2, q = t & 3;
    const int aa = a0 + (r & 7), bb = b0 + (r >> 3);
    const float4* xrow = reinterpret_cast<const float4*>(x + ((size_t)aa * Ns + bb) * Dd);
    float4 xv[8];
#pragma unroll
    for (int i2 = 0; i2 < 8; ++i2) xv[i2] = xrow[q + 4 * i2];
    if (t < 128){ gln[t] = g_ln[t]; bln[t] = b_ln[t]; }

    float s1 = 0.f, s2 = 0.f;
#pragma unroll
    for (int i2 = 0; i2 < 8; ++i2){
        float4 v = xv[i2];
        s1 += v.x + v.y + v.z + v.w;
        s2 += v.x * v.x + v.y * v.y + v.z * v.z + v.w * v.w;
    }
    s1 += __shfl_xor(s1, 1); s1 += __shfl_xor(s1, 2);
    s2 += __shfl_xor(s2, 1); s2 += __shfl_xor(s2, 2);
    const float mm  = s1 * (1.0f / 128.0f);
    const float rsv = rsqrtf(s2 * (1.0f / 128.0f) - mm * mm + EPSV);
    __syncthreads();                   // (1) gln/bln ready
#pragma unroll
    for (int i2 = 0; i2 < 8; ++i2){
        const int d = (q + 4 * i2) * 4;
        ushort4 o;
        o.x = f2bf((xv[i2].x - mm) * rsv * gln[d + 0] + bln[d + 0]);
        o.y = f2bf((xv[i2].y - mm) * rsv * gln[d + 1] + bln[d + 1]);
        o.z = f2bf((xv[i2].z - mm) * rsv * gln[d + 2] + bln[d + 2]);
        o.w = f2bf((xv[i2].w - mm) * rsv * gln[d + 3] + bln[d + 3]);
        *reinterpret_cast<ushort4*>(&SB[r * 136 + d]) = o;
    }
    __syncthreads();                   // (2) xn ready (read-only afterwards)

    u16* SBw = &SB2[w * 32 * 68];      // wave-private staging (32 cols x 68)
    const f32x4 zero4 = {0.f, 0.f, 0.f, 0.f};
    f32x4 aV[4], aG[4];

    // GEMM one cf group; A-fragments read from LDS per ks (transient 32 regs)
    auto GEMM1 = [&](const u16* WV, const u16* WG, int cf){
        const int col = nb + cf * 16 + lrow;
#pragma unroll
        for (int rf = 0; rf < 4; ++rf){ aV[rf] = zero4; aG[rf] = zero4; }
#pragma unroll
        for (int ks = 0; ks < 4; ++ks){
            bf16x8 afr[4];
#pragma unroll
            for (int rf = 0; rf < 4; ++rf)
                afr[rf] = *reinterpret_cast<const bf16x8*>(&SB[(rf * 16 + lrow) * 136 + ks * 32 + g * 8]);
            bf16x8 bv = *reinterpret_cast<const bf16x8*>(WV + (size_t)col * 128 + ks * 32 + g * 8);
            bf16x8 bg = *reinterpret_cast<const bf16x8*>(WG + (size_t)col * 128 + ks * 32 + g * 8);
#pragma unroll
            for (int rf = 0; rf < 4; ++rf)
                aV[rf] = __builtin_amdgcn_mfma_f32_16x16x32_bf16(afr[rf], bv, aV[rf], 0, 0, 0);
#pragma unroll
            for (int rf = 0; rf < 4; ++rf)
                aG[rf] = __builtin_amdgcn_mfma_f32_16x16x32_bf16(afr[rf], bg, aG[rf], 0, 0, 0);
        }
    };
    auto STW = [&](const float* bV, const float* bG, int cf){
        const int cl2 = cf * 16 + lrow;
        const int col = nb + cl2;
        const float bVv = bV[col], bGv = bG[col];
#pragma unroll
        for (int rf = 0; rf < 4; ++rf){
            ushort4 pk;
#pragma unroll
            for (int j = 0; j < 4; ++j){
                const float vv = aV[rf][j] + bVv;
                const float gg = aG[rf][j] + bGv;
                ((u16*)&pk)[j] = f2bf(sigmoidf_(gg) * vv);
            }
            *reinterpret_cast<ushort4*>(&SBw[cl2 * 68 + rf * 16 + orow]) = pk;
        }
    };
    auto STORE = [&](u16* dst){
#pragma unroll
        for (int it = 0; it < 4; ++it){
            const int cl2 = it * 8 + (l >> 3);
            const int s   = l & 7;
            int4 v = *reinterpret_cast<const int4*>(&SBw[cl2 * 68 + s * 8]);
            *reinterpret_cast<int4*>(dst + (((size_t)(nb + cl2) * 64 + kb) * Ns + b0) * 8 + s * 8) = v;
        }
    };

    // ---- L/R pipeline (wave-private; fences order same-wave LDS reuse) ----
    GEMM1(Wt,             Wt + 16384,     0); STW(bl, blg, 0);
    GEMM1(Wt,             Wt + 16384,     1); STW(bl, blg, 1);
    LDS_FENCE;
    STORE(left);
    LDS_FENCE;
    GEMM1(Wt + 2 * 16384, Wt + 3 * 16384, 0); STW(br, brg, 0);
    GEMM1(Wt + 2 * 16384, Wt + 3 * 16384, 1); STW(br, brg, 1);
    LDS_FENCE;
    STORE(right);
    __syncthreads();           // (3) all waves done with wp staging; SB2 -> og layout

    // ---- og: GEMM (V only, af from LDS), block stage [64][132], int2 stores ----
    {
        const u16* WO = Wt + (size_t)4 * 16384;
        u16* lS = &SB2[0];
#pragma unroll 1
        for (int cf = 0; cf < 2; ++cf){
            const int col = nb + cf * 16 + lrow;
#pragma unroll
            for (int rf = 0; rf < 4; ++rf) aV[rf] = zero4;
#pragma unroll
            for (int ks = 0; ks < 4; ++ks){
                bf16x8 afr[4];
#pragma unroll
                for (int rf = 0; rf < 4; ++rf)
                    afr[rf] = *reinterpret_cast<const bf16x8*>(&SB[(rf * 16 + lrow) * 136 + ks * 32 + g * 8]);
                bf16x8 bv = *reinterpret_cast<const bf16x8*>(WO + (size_t)col * 128 + ks * 32 + g * 8);
#pragma unroll
                for (int rf = 0; rf < 4; ++rf)
                    aV[rf] = __builtin_amdgcn_mfma_f32_16x16x32_bf16(afr[rf], bv, aV[rf], 0, 0, 0);
            }
            const float bOv = bog[col];
#pragma unroll
            for (int rf = 0; rf < 4; ++rf)
#pragma unroll
                for (int j = 0; j < 4; ++j){
                    const int row = rf * 16 + orow + j;
                    lS[row * 132 + col] = f2bf(sigmoidf_(aV[rf][j] + bOv));
                }
        }
        __syncthreads();       // (4) og staging ready
        const int bsub = t >> 5, c4 = (t & 31) * 4;
#pragma unroll
        for (int a = 0; a < 8; ++a){
            const int row = bsub * 8 + a;
            int2 v = *reinterpret_cast<const int2*>(&lS[row * 132 + c4]);
            *reinterpret_cast<int2*>(og + (((size_t)(a0 + a) * Ns) + (b0 + bsub)) * Cc + c4) = v;
        }
    }
}

// ---------------------------------------------------------------------------
// K2: om[c][i][j] = sum_k left[c][k][i] * right[c][k][j]   (per-channel GEMM)
// 1-D grid 2048, XCD-swizzled so each XCD owns 16 whole channels.  (frozen)
// ---------------------------------------------------------------------------
#define K2_LOAD(AF, BF, KS) do {                                                    \
    const size_t kbrow_ = (size_t)((KS) * 4 + lkb) * Ns;                            \
    _Pragma("unroll") for (int rf = 0; rf < 4; ++rf)                                \
        AF[rf] = *reinterpret_cast<const bf16x8*>(Lc + (kbrow_ + ib + rf * 16 + lrow) * 8); \
    _Pragma("unroll") for (int cf = 0; cf < 4; ++cf)                                \
        BF[cf] = *reinterpret_cast<const bf16x8*>(Rc + (kbrow_ + jb + cf * 16 + lrow) * 8); \
} while (0)

#define K2_MM(AF, BF) do {                                                          \
    _Pragma("unroll") for (int rf = 0; rf < 4; ++rf)                                \
    _Pragma("unroll") for (int cf = 0; cf < 4; ++cf)                                \
        acc[rf][cf] = __builtin_amdgcn_mfma_f32_16x16x32_bf16(AF[rf], BF[cf], acc[rf][cf], 0, 0, 0); \
} while (0)

__global__ __launch_bounds__(256) void k2(const u16* __restrict__ left,
                                          const u16* __restrict__ right,
                                          u16* __restrict__ om)
{
    __shared__ u16 sO[128][136];
    const int bid = blockIdx.x;
    const int xcd = bid & 7, idxx = bid >> 3;
    const int virt = xcd * 256 + idxx;
    const int c    = virt >> 4;
    const int tile = virt & 15;
    const int iy = tile >> 2, jx = tile & 3;
    const int t = threadIdx.x, w = t >> 6, l = t & 63;
    const int wr = w >> 1, wc = w & 1;
    const int ib = iy * 128 + wr * 64;
    const int jb = jx * 128 + wc * 64;
    const int lrow = l & 15, lkb = l >> 4;
    const u16* Lc = left  + (size_t)c * (Ns * Ns);
    const u16* Rc = right + (size_t)c * (Ns * Ns);
    const f32x4 zero4 = {0.f, 0.f, 0.f, 0.f};
    f32x4 acc[4][4];
#pragma unroll
    for (int rf = 0; rf < 4; ++rf)
#pragma unroll
        for (int cf = 0; cf < 4; ++cf) acc[rf][cf] = zero4;

    bf16x8 a0f[4], b0f[4], a1f[4], b1f[4];
    K2_LOAD(a0f, b0f, 0);
#pragma unroll
    for (int ks = 0; ks < 16; ks += 2){
        K2_LOAD(a1f, b1f, ks + 1);
        K2_MM(a0f, b0f);
        if (ks + 2 < 16) K2_LOAD(a0f, b0f, ks + 2);
        K2_MM(a1f, b1f);
    }

    const int orow = (l >> 4) << 2;
#pragma unroll
    for (int rf = 0; rf < 4; ++rf)
#pragma unroll
        for (int j2 = 0; j2 < 4; ++j2){
            const int rloc = wr * 64 + rf * 16 + orow + j2;
#pragma unroll
            for (int cf = 0; cf < 4; ++cf)
                sO[rloc][wc * 64 + cf * 16 + lrow] = f2bf(acc[rf][cf][j2]);
        }
    __syncthreads();
    u16* obase = om + (size_t)c * Ns * Ns + (size_t)(iy * 128) * Ns + jx * 128;
#pragma unroll
    for (int s = 0; s < 8; ++s){
        const int gg = s * 256 + t;
        const int row = gg >> 4, co = (gg & 15) * 8;
        int4 v = *reinterpret_cast<const int4*>(&sO[row][co]);
        *reinterpret_cast<int4*>(obase + (size_t)row * Ns + co) = v;
    }
}

// ---------------------------------------------------------------------------
// K3: final = sigmoid(og) * (LN_c(out_mid) @ Wo + bo), fp32 out  (R8-verified)
// ---------------------------------------------------------------------------
__global__ __launch_bounds__(256) void k3(
    const u16* __restrict__ om, const u16* __restrict__ og, const u16* __restrict__ Wt,
    const float* __restrict__ g2, const float* __restrict__ b2, const float* __restrict__ bo,
    float* __restrict__ out)
{
    __shared__ char smem[34816];
    u16* X = reinterpret_cast<u16*>(smem);
    u16* O = reinterpret_cast<u16*>(smem) + 8704;
    __shared__ float sg2[128], sb2[128];
    const int i  = blockIdx.y;
    const int j0 = blockIdx.x * 64;
    const int t  = threadIdx.x;
    if (t < 128){ sg2[t] = g2[t]; sb2[t] = b2[t]; }
    {
        const int c = t >> 1, jh = (t & 1) * 32;
        const u16* src = om + (size_t)c * Ns * Ns + (size_t)i * Ns + j0 + jh;
#pragma unroll
        for (int s = 0; s < 8; ++s){
            ushort4 v = reinterpret_cast<const ushort4*>(src)[s];
            const int jj = jh + s * 4;
            X[(jj + 0) * 136 + c] = v.x; X[(jj + 1) * 136 + c] = v.y;
            X[(jj + 2) * 136 + c] = v.z; X[(jj + 3) * 136 + c] = v.w;
        }
    }
    {
        const int jj = t >> 2, qq = t & 3;
        const u16* src = og + ((size_t)i * Ns + j0 + jj) * Cc + qq * 32;
#pragma unroll
        for (int s = 0; s < 4; ++s)
            *reinterpret_cast<int4*>(&O[jj * 136 + qq * 32 + s * 8]) = reinterpret_cast<const int4*>(src)[s];
    }
    __syncthreads();
    const int r = t >> 2, q = t & 3;
    {
        float s1 = 0.f, s2v = 0.f;
#pragma unroll
        for (int e = 0; e < 32; ++e){
            const float v = bf2f(X[r * 136 + q * 32 + e]);
            s1 += v; s2v += v * v;
        }
        s1  += __shfl_xor(s1, 1);  s1  += __shfl_xor(s1, 2);
        s2v += __shfl_xor(s2v, 1); s2v += __shfl_xor(s2v, 2);
        const float mm  = s1 * (1.0f / 128.0f);
        const float rsv = rsqrtf(s2v * (1.0f / 128.0f) - mm * mm + EPSV);
#pragma unroll
        for (int e = 0; e < 32; ++e){
            const int cc = q * 32 + e;
            const float v = bf2f(X[r * 136 + cc]);
            X[r * 136 + cc] = f2bf((v - mm) * rsv * sg2[cc] + sb2[cc]);
        }
    }
    __syncthreads();
    const int w = t >> 6, l = t & 63;
    const int lrow = l & 15, lk = (l >> 4) << 3, nbv = w * 32, orow = (l >> 4) << 2;
    const u16* WO = Wt + (size_t)5 * 16384;
    const f32x4 zero4 = {0.f, 0.f, 0.f, 0.f};
    f32x4 acc[4][2];
#pragma unroll
    for (int rf = 0; rf < 4; ++rf)
#pragma unroll
        for (int cf = 0; cf < 2; ++cf) acc[rf][cf] = zero4;
#pragma unroll
    for (int ks = 0; ks < 4; ++ks){
        const int k0 = ks * 32 + lk;
        bf16x8 af[4];
#pragma unroll
        for (int rf = 0; rf < 4; ++rf)
            af[rf] = *reinterpret_cast<const bf16x8*>(&X[(rf * 16 + lrow) * 136 + k0]);
#pragma unroll
        for (int cf = 0; cf < 2; ++cf){
            bf16x8 bv = *reinterpret_cast<const bf16x8*>(WO + (size_t)(nbv + cf * 16 + lrow) * 128 + k0);
#pragma unroll
            for (int rf = 0; rf < 4; ++rf)
                acc[rf][cf] = __builtin_amdgcn_mfma_f32_16x16x32_bf16(af[rf], bv, acc[rf][cf], 0, 0, 0);
        }
    }
    float gv[2][4][4];
#pragma unroll
    for (int cf = 0; cf < 2; ++cf){
        const int cg = nbv + cf * 16 + lrow;
        const float bov = bo[cg];
#pragma unroll
        for (int rf = 0; rf < 4; ++rf)
#pragma unroll
            for (int j = 0; j < 4; ++j){
                const int row = rf * 16 + orow + j;
                gv[cf][rf][j] = bf2f(O[row * 136 + cg]) * (acc[rf][cf][j] + bov);
            }
    }
    __syncthreads();
    float* sF = reinterpret_cast<float*>(smem);
#pragma unroll
    for (int cf = 0; cf < 2; ++cf){
        const int cg = nbv + cf * 16 + lrow;
#pragma unroll
        for (int rf = 0; rf < 4; ++rf)
#pragma unroll
            for (int j = 0; j < 4; ++j){
                const int row = rf * 16 + orow + j;
                sF[row * 128 + cg] = gv[cf][rf][j];
            }
    }
    __syncthreads();
    const float4* sF4 = reinterpret_cast<const float4*>(smem);
    float* obase = out + ((size_t)i * Ns + j0) * Cc;
#pragma unroll
    for (int s = 0; s < 8; ++s){
        const int gg = s * 256 + t;
        const int row = gg >> 5, co = (gg & 31) * 4;
        float4 v = sF4[gg];
        *reinterpret_cast<float4*>(obase + (size_t)row * Cc + co) = v;
    }
}

// ---------------------------------------------------------------------------
extern "C" void kernel_launch(void* const* d_in, const int* in_sizes, int n_in,
                              void* d_out, int out_size, void* d_ws, size_t ws_size,
                              hipStream_t stream)
{
    const float* x    = (const float*)d_in[0];
    const float* ling = (const float*)d_in[1];
    const float* linb = (const float*)d_in[2];
    const float* loutg= (const float*)d_in[3];
    const float* loutb= (const float*)d_in[4];
    const float* Wl   = (const float*)d_in[5];
    const float* bl   = (const float*)d_in[6];
    const float* Wr   = (const float*)d_in[7];
    const float* br   = (const float*)d_in[8];
    const float* Wo   = (const float*)d_in[9];
    const float* bo   = (const float*)d_in[10];
    const float* Wlg  = (const float*)d_in[11];
    const float* blg  = (const float*)d_in[12];
    const float* Wrg  = (const float*)d_in[13];
    const float* brg  = (const float*)d_in[14];
    const float* Wog  = (const float*)d_in[15];
    const float* bog  = (const float*)d_in[16];

    char* ws = (char*)d_ws;
    u16* Wt = (u16*)ws;
    const size_t off = 256 * 1024;
    const size_t SZ  = (size_t)33554432 * 2;   // 64 MiB per bf16 tensor
    u16* left  = (u16*)(ws + off);
    u16* right = (u16*)(ws + off + SZ);
    u16* og    = (u16*)(ws + off + 2 * SZ);
    u16* om    = (u16*)(ws + off + 3 * SZ);

    hipLaunchKernelGGL(k_prep, dim3(384), dim3(256), 0, stream, Wl, Wlg, Wr, Wrg, Wog, Wo, Wt);
    hipLaunchKernelGGL(k1, dim3(4096), dim3(256), 0, stream,
                       x, ling, linb, Wt, bl, blg, br, brg, bog, left, right, og);
    hipLaunchKernelGGL(k2, dim3(2048), dim3(256), 0, stream, left, right, om);
    hipLaunchKernelGGL(k3, dim3(8, 512), dim3(256), 0, stream, om, og, Wt, loutg, loutb, bo, (float*)d_out);
}

// Round 15
// 254.321 us; speedup vs baseline: 1.0825x; 1.0132x over previous
//
#include <hip/hip_runtime.h>
#include <hip/hip_bf16.h>
#include <cstdint>
#include <cstddef>

typedef unsigned short u16;
typedef short bf16x8 __attribute__((ext_vector_type(8)));
typedef float f32x4 __attribute__((ext_vector_type(4)));

constexpr int Ns = 512;   // N
constexpr int Dd = 128;   // D
constexpr int Cc = 128;   // C
#define EPSV 1e-5f

__device__ __forceinline__ u16 f2bf(float f){
    __hip_bfloat16 h = __float2bfloat16(f);
    return *reinterpret_cast<u16*>(&h);
}
__device__ __forceinline__ float bf2f(u16 h){
    return __uint_as_float(((uint32_t)h) << 16);
}
__device__ __forceinline__ float sigmoidf_(float x){
    return __builtin_amdgcn_rcpf(1.0f + __expf(-x));   // rcp: ~1ulp, fine at bf16
}

// ---------------------------------------------------------------------------
// K0: weights -> bf16, transposed [n][k].  Order: Wl,Wlg,Wr,Wrg,Wog,Wo
// (R4-verified linear layout)
// ---------------------------------------------------------------------------
__global__ void k_prep(const float* __restrict__ Wl, const float* __restrict__ Wlg,
                       const float* __restrict__ Wr, const float* __restrict__ Wrg,
                       const float* __restrict__ Wog, const float* __restrict__ Wo,
                       u16* __restrict__ Wt){
    int idx = blockIdx.x * 256 + threadIdx.x;
    if (idx >= 6 * 16384) return;
    int m = idx >> 14; int nk = idx & 16383; int n = nk >> 7; int k = nk & 127;
    const float* W = (m == 0) ? Wl : (m == 1) ? Wlg : (m == 2) ? Wr
                   : (m == 3) ? Wrg : (m == 4) ? Wog : Wo;
    Wt[idx] = f2bf(W[k * Cc + n]);
}

// ---------------------------------------------------------------------------
// K1: LN(x) then 5 GEMMs (Wl,Wlg -> left; Wr,Wrg -> right; Wog -> og)
// Block: 64 rows = 8 a x 8 b.  256 threads / 4 waves.
// One shared buffer SB aliased across barrier-separated phases:
//   phase 1: xn tile [64][136]      (source of af registers)
//   phase 2: left stage [128][68]   (gated bf16, then coalesced int4 store)
//   phase 3: right stage [128][68]
//   phase 4: og stage [64][132]     (then coalesced int2 store)
// Per-cf accumulators (32 live) + af[4][4] (64); no B double buffer.
// Epilogue global stores are 128B-coalesced.   (R8 — measured best: 140 us)
// ---------------------------------------------------------------------------
__global__ __launch_bounds__(256) void k1(
    const float* __restrict__ x, const float* __restrict__ g_ln, const float* __restrict__ b_ln,
    const u16* __restrict__ Wt,
    const float* __restrict__ bl, const float* __restrict__ blg,
    const float* __restrict__ br, const float* __restrict__ brg,
    const float* __restrict__ bog,
    u16* __restrict__ left, u16* __restrict__ right, u16* __restrict__ og)
{
    __shared__ u16  SB[8704];          // 17.0 KB, aliased phases (all barrier-protected)
    __shared__ float gln[128], bln[128];

    const int t   = threadIdx.x;
    const int bid = blockIdx.x;
    const int a0  = (bid >> 6) << 3;
    const int b0  = (bid & 63) << 3;
    const int w = t >> 6, l = t & 63;
    const int lrow = l & 15, g = l >> 4;
    const int nb = w * 32;
    const int orow = g << 2;
    const int kb = a0 >> 3;

    // ---- prologue: x loads, LN stats, normalize into SB-as-lA ----
    const int r = t >> 2, q = t & 3;
    const int aa = a0 + (r & 7), bb = b0 + (r >> 3);
    const float4* xrow = reinterpret_cast<const float4*>(x + ((size_t)aa * Ns + bb) * Dd);
    float4 xv[8];
#pragma unroll
    for (int i2 = 0; i2 < 8; ++i2) xv[i2] = xrow[q + 4 * i2];
    if (t < 128){ gln[t] = g_ln[t]; bln[t] = b_ln[t]; }

    float s1 = 0.f, s2 = 0.f;
#pragma unroll
    for (int i2 = 0; i2 < 8; ++i2){
        float4 v = xv[i2];
        s1 += v.x + v.y + v.z + v.w;
        s2 += v.x * v.x + v.y * v.y + v.z * v.z + v.w * v.w;
    }
    s1 += __shfl_xor(s1, 1); s1 += __shfl_xor(s1, 2);
    s2 += __shfl_xor(s2, 1); s2 += __shfl_xor(s2, 2);
    const float mm  = s1 * (1.0f / 128.0f);
    const float rsv = rsqrtf(s2 * (1.0f / 128.0f) - mm * mm + EPSV);
    __syncthreads();                   // gln/bln ready
#pragma unroll
    for (int i2 = 0; i2 < 8; ++i2){
        const int d = (q + 4 * i2) * 4;
        ushort4 o;
        o.x = f2bf((xv[i2].x - mm) * rsv * gln[d + 0] + bln[d + 0]);
        o.y = f2bf((xv[i2].y - mm) * rsv * gln[d + 1] + bln[d + 1]);
        o.z = f2bf((xv[i2].z - mm) * rsv * gln[d + 2] + bln[d + 2]);
        o.w = f2bf((xv[i2].w - mm) * rsv * gln[d + 3] + bln[d + 3]);
        *reinterpret_cast<ushort4*>(&SB[r * 136 + d]) = o;
    }
    __syncthreads();                   // xn ready

    // ---- A-fragments once (R4-verified) ----
    bf16x8 af[4][4];
#pragma unroll
    for (int ks = 0; ks < 4; ++ks)
#pragma unroll
        for (int rf = 0; rf < 4; ++rf)
            af[ks][rf] = *reinterpret_cast<const bf16x8*>(&SB[(rf * 16 + lrow) * 136 + ks * 32 + g * 8]);
    __syncthreads();                   // all af reads done; SB free for staging

    const f32x4 zero4 = {0.f, 0.f, 0.f, 0.f};
    f32x4 aV[4], aG[4];

    // GEMM one cf group of a V/G pair (acc live: 32 regs)
    auto GEMM1 = [&](const u16* WV, const u16* WG, int cf){
        const int col = nb + cf * 16 + lrow;
#pragma unroll
        for (int rf = 0; rf < 4; ++rf){ aV[rf] = zero4; aG[rf] = zero4; }
#pragma unroll
        for (int ks = 0; ks < 4; ++ks){
            bf16x8 bv = *reinterpret_cast<const bf16x8*>(WV + (size_t)col * 128 + ks * 32 + g * 8);
            bf16x8 bg = *reinterpret_cast<const bf16x8*>(WG + (size_t)col * 128 + ks * 32 + g * 8);
#pragma unroll
            for (int rf = 0; rf < 4; ++rf)
                aV[rf] = __builtin_amdgcn_mfma_f32_16x16x32_bf16(af[ks][rf], bv, aV[rf], 0, 0, 0);
#pragma unroll
            for (int rf = 0; rf < 4; ++rf)
                aG[rf] = __builtin_amdgcn_mfma_f32_16x16x32_bf16(af[ks][rf], bg, aG[rf], 0, 0, 0);
        }
    };
    // gate + stage into SB[col][r_tile] (stride 68; r_tile = rf*16+orow+j)
    auto STW = [&](const float* bV, const float* bG, int cf){
        const int col = nb + cf * 16 + lrow;
        const float bVv = bV[col], bGv = bG[col];
#pragma unroll
        for (int rf = 0; rf < 4; ++rf){
            ushort4 pk;
#pragma unroll
            for (int j = 0; j < 4; ++j){
                const float vv = aV[rf][j] + bVv;
                const float gg = aG[rf][j] + bGv;
                ((u16*)&pk)[j] = f2bf(sigmoidf_(gg) * vv);
            }
            *reinterpret_cast<ushort4*>(&SB[col * 68 + rf * 16 + orow]) = pk;
        }
    };
    // coalesced store: per c, 64 contiguous u16 (=128B); 8 threads cover one c
    auto STORE = [&](u16* dst){
#pragma unroll
        for (int it = 0; it < 4; ++it){
            const int cl = it * 32 + (t >> 3);
            const int s  = t & 7;
            int4 v = *reinterpret_cast<const int4*>(&SB[cl * 68 + s * 8]);
            *reinterpret_cast<int4*>(dst + (((size_t)cl * 64 + kb) * Ns + b0) * 8 + s * 8) = v;
        }
    };

    // ---- L pair ----
    GEMM1(Wt,             Wt + 16384,     0); STW(bl, blg, 0);
    GEMM1(Wt,             Wt + 16384,     1); STW(bl, blg, 1);
    __syncthreads();
    STORE(left);
    __syncthreads();
    // ---- R pair ----
    GEMM1(Wt + 2 * 16384, Wt + 3 * 16384, 0); STW(br, brg, 0);
    GEMM1(Wt + 2 * 16384, Wt + 3 * 16384, 1); STW(br, brg, 1);
    __syncthreads();
    STORE(right);
    __syncthreads();

    // ---- og: GEMM (V only), stage [64][132], coalesced int2 store ----
    const u16* WO = Wt + (size_t)4 * 16384;
#pragma unroll 1
    for (int cf = 0; cf < 2; ++cf){
        const int col = nb + cf * 16 + lrow;
#pragma unroll
        for (int rf = 0; rf < 4; ++rf) aV[rf] = zero4;
#pragma unroll
        for (int ks = 0; ks < 4; ++ks){
            bf16x8 bv = *reinterpret_cast<const bf16x8*>(WO + (size_t)col * 128 + ks * 32 + g * 8);
#pragma unroll
            for (int rf = 0; rf < 4; ++rf)
                aV[rf] = __builtin_amdgcn_mfma_f32_16x16x32_bf16(af[ks][rf], bv, aV[rf], 0, 0, 0);
        }
        const float bOv = bog[col];
#pragma unroll
        for (int rf = 0; rf < 4; ++rf)
#pragma unroll
            for (int j = 0; j < 4; ++j){
                const int row = rf * 16 + orow + j;
                SB[row * 132 + col] = f2bf(sigmoidf_(aV[rf][j] + bOv));
            }
    }
    __syncthreads();
    const int bsub = t >> 5, c4 = (t & 31) * 4;
#pragma unroll
    for (int a = 0; a < 8; ++a){
        const int row = bsub * 8 + a;
        int2 v = *reinterpret_cast<const int2*>(&SB[row * 132 + c4]);
        *reinterpret_cast<int2*>(og + (((size_t)(a0 + a) * Ns) + (b0 + bsub)) * Cc + c4) = v;
    }
}

// ---------------------------------------------------------------------------
// K2: om[c][i][j] = sum_k left[c][k][i] * right[c][k][j]   (per-channel GEMM)
// 1-D grid 2048, XCD-swizzled so each XCD owns 16 whole channels.
// ---------------------------------------------------------------------------
#define K2_LOAD(AF, BF, KS) do {                                                    \
    const size_t kbrow_ = (size_t)((KS) * 4 + lkb) * Ns;                            \
    _Pragma("unroll") for (int rf = 0; rf < 4; ++rf)                                \
        AF[rf] = *reinterpret_cast<const bf16x8*>(Lc + (kbrow_ + ib + rf * 16 + lrow) * 8); \
    _Pragma("unroll") for (int cf = 0; cf < 4; ++cf)                                \
        BF[cf] = *reinterpret_cast<const bf16x8*>(Rc + (kbrow_ + jb + cf * 16 + lrow) * 8); \
} while (0)

#define K2_MM(AF, BF) do {                                                          \
    _Pragma("unroll") for (int rf = 0; rf < 4; ++rf)                                \
    _Pragma("unroll") for (int cf = 0; cf < 4; ++cf)                                \
        acc[rf][cf] = __builtin_amdgcn_mfma_f32_16x16x32_bf16(AF[rf], BF[cf], acc[rf][cf], 0, 0, 0); \
} while (0)

__global__ __launch_bounds__(256) void k2(const u16* __restrict__ left,
                                          const u16* __restrict__ right,
                                          u16* __restrict__ om)
{
    __shared__ u16 sO[128][136];
    const int bid = blockIdx.x;
    const int xcd = bid & 7, idxx = bid >> 3;
    const int virt = xcd * 256 + idxx;
    const int c    = virt >> 4;
    const int tile = virt & 15;
    const int iy = tile >> 2, jx = tile & 3;
    const int t = threadIdx.x, w = t >> 6, l = t & 63;
    const int wr = w >> 1, wc = w & 1;
    const int ib = iy * 128 + wr * 64;
    const int jb = jx * 128 + wc * 64;
    const int lrow = l & 15, lkb = l >> 4;
    const u16* Lc = left  + (size_t)c * (Ns * Ns);
    const u16* Rc = right + (size_t)c * (Ns * Ns);
    const f32x4 zero4 = {0.f, 0.f, 0.f, 0.f};
    f32x4 acc[4][4];
#pragma unroll
    for (int rf = 0; rf < 4; ++rf)
#pragma unroll
        for (int cf = 0; cf < 4; ++cf) acc[rf][cf] = zero4;

    bf16x8 a0f[4], b0f[4], a1f[4], b1f[4];
    K2_LOAD(a0f, b0f, 0);
#pragma unroll
    for (int ks = 0; ks < 16; ks += 2){
        K2_LOAD(a1f, b1f, ks + 1);
        K2_MM(a0f, b0f);
        if (ks + 2 < 16) K2_LOAD(a0f, b0f, ks + 2);
        K2_MM(a1f, b1f);
    }

    const int orow = (l >> 4) << 2;
#pragma unroll
    for (int rf = 0; rf < 4; ++rf)
#pragma unroll
        for (int j2 = 0; j2 < 4; ++j2){
            const int rloc = wr * 64 + rf * 16 + orow + j2;
#pragma unroll
            for (int cf = 0; cf < 4; ++cf)
                sO[rloc][wc * 64 + cf * 16 + lrow] = f2bf(acc[rf][cf][j2]);
        }
    __syncthreads();
    u16* obase = om + (size_t)c * Ns * Ns + (size_t)(iy * 128) * Ns + jx * 128;
#pragma unroll
    for (int s = 0; s < 8; ++s){
        const int gg = s * 256 + t;
        const int row = gg >> 4, co = (gg & 15) * 8;
        int4 v = *reinterpret_cast<const int4*>(&sO[row][co]);
        *reinterpret_cast<int4*>(obase + (size_t)row * Ns + co) = v;
    }
}

// ---------------------------------------------------------------------------
// K3: final = sigmoid(og) * (LN_c(out_mid) @ Wo + bo), fp32 out [i][j][c]
// ---------------------------------------------------------------------------
__global__ __launch_bounds__(256) void k3(
    const u16* __restrict__ om, const u16* __restrict__ og, const u16* __restrict__ Wt,
    const float* __restrict__ g2, const float* __restrict__ b2, const float* __restrict__ bo,
    float* __restrict__ out)
{
    __shared__ char smem[34816];
    u16* X = reinterpret_cast<u16*>(smem);
    u16* O = reinterpret_cast<u16*>(smem) + 8704;
    __shared__ float sg2[128], sb2[128];
    const int i  = blockIdx.y;
    const int j0 = blockIdx.x * 64;
    const int t  = threadIdx.x;
    if (t < 128){ sg2[t] = g2[t]; sb2[t] = b2[t]; }
    {
        const int c = t >> 1, jh = (t & 1) * 32;
        const u16* src = om + (size_t)c * Ns * Ns + (size_t)i * Ns + j0 + jh;
#pragma unroll
        for (int s = 0; s < 8; ++s){
            ushort4 v = reinterpret_cast<const ushort4*>(src)[s];
            const int jj = jh + s * 4;
            X[(jj + 0) * 136 + c] = v.x; X[(jj + 1) * 136 + c] = v.y;
            X[(jj + 2) * 136 + c] = v.z; X[(jj + 3) * 136 + c] = v.w;
        }
    }
    {
        const int jj = t >> 2, qq = t & 3;
        const u16* src = og + ((size_t)i * Ns + j0 + jj) * Cc + qq * 32;
#pragma unroll
        for (int s = 0; s < 4; ++s)
            *reinterpret_cast<int4*>(&O[jj * 136 + qq * 32 + s * 8]) = reinterpret_cast<const int4*>(src)[s];
    }
    __syncthreads();
    const int r = t >> 2, q = t & 3;
    {
        float s1 = 0.f, s2v = 0.f;
#pragma unroll
        for (int e = 0; e < 32; ++e){
            const float v = bf2f(X[r * 136 + q * 32 + e]);
            s1 += v; s2v += v * v;
        }
        s1  += __shfl_xor(s1, 1);  s1  += __shfl_xor(s1, 2);
        s2v += __shfl_xor(s2v, 1); s2v += __shfl_xor(s2v, 2);
        const float mm  = s1 * (1.0f / 128.0f);
        const float rsv = rsqrtf(s2v * (1.0f / 128.0f) - mm * mm + EPSV);
#pragma unroll
        for (int e = 0; e < 32; ++e){
            const int cc = q * 32 + e;
            const float v = bf2f(X[r * 136 + cc]);
            X[r * 136 + cc] = f2bf((v - mm) * rsv * sg2[cc] + sb2[cc]);
        }
    }
    __syncthreads();
    const int w = t >> 6, l = t & 63;
    const int lrow = l & 15, lk = (l >> 4) << 3, nbv = w * 32, orow = (l >> 4) << 2;
    const u16* WO = Wt + (size_t)5 * 16384;
    const f32x4 zero4 = {0.f, 0.f, 0.f, 0.f};
    f32x4 acc[4][2];
#pragma unroll
    for (int rf = 0; rf < 4; ++rf)
#pragma unroll
        for (int cf = 0; cf < 2; ++cf) acc[rf][cf] = zero4;
#pragma unroll
    for (int ks = 0; ks < 4; ++ks){
        const int k0 = ks * 32 + lk;
        bf16x8 af[4];
#pragma unroll
        for (int rf = 0; rf < 4; ++rf)
            af[rf] = *reinterpret_cast<const bf16x8*>(&X[(rf * 16 + lrow) * 136 + k0]);
#pragma unroll
        for (int cf = 0; cf < 2; ++cf){
            bf16x8 bv = *reinterpret_cast<const bf16x8*>(WO + (size_t)(nbv + cf * 16 + lrow) * 128 + k0);
#pragma unroll
            for (int rf = 0; rf < 4; ++rf)
                acc[rf][cf] = __builtin_amdgcn_mfma_f32_16x16x32_bf16(af[rf], bv, acc[rf][cf], 0, 0, 0);
        }
    }
    float gv[2][4][4];
#pragma unroll
    for (int cf = 0; cf < 2; ++cf){
        const int cg = nbv + cf * 16 + lrow;
        const float bov = bo[cg];
#pragma unroll
        for (int rf = 0; rf < 4; ++rf)
#pragma unroll
            for (int j = 0; j < 4; ++j){
                const int row = rf * 16 + orow + j;
                gv[cf][rf][j] = bf2f(O[row * 136 + cg]) * (acc[rf][cf][j] + bov);
            }
    }
    __syncthreads();
    float* sF = reinterpret_cast<float*>(smem);
#pragma unroll
    for (int cf = 0; cf < 2; ++cf){
        const int cg = nbv + cf * 16 + lrow;
#pragma unroll
        for (int rf = 0; rf < 4; ++rf)
#pragma unroll
            for (int j = 0; j < 4; ++j){
                const int row = rf * 16 + orow + j;
                sF[row * 128 + cg] = gv[cf][rf][j];
            }
    }
    __syncthreads();
    const float4* sF4 = reinterpret_cast<const float4*>(smem);
    float* obase = out + ((size_t)i * Ns + j0) * Cc;
#pragma unroll
    for (int s = 0; s < 8; ++s){
        const int gg = s * 256 + t;
        const int row = gg >> 5, co = (gg & 31) * 4;
        float4 v = sF4[gg];
        *reinterpret_cast<float4*>(obase + (size_t)row * Cc + co) = v;
    }
}

// ---------------------------------------------------------------------------
extern "C" void kernel_launch(void* const* d_in, const int* in_sizes, int n_in,
                              void* d_out, int out_size, void* d_ws, size_t ws_size,
                              hipStream_t stream)
{
    const float* x    = (const float*)d_in[0];
    const float* ling = (const float*)d_in[1];
    const float* linb = (const float*)d_in[2];
    const float* loutg= (const float*)d_in[3];
    const float* loutb= (const float*)d_in[4];
    const float* Wl   = (const float*)d_in[5];
    const float* bl   = (const float*)d_in[6];
    const float* Wr   = (const float*)d_in[7];
    const float* br   = (const float*)d_in[8];
    const float* Wo   = (const float*)d_in[9];
    const float* bo   = (const float*)d_in[10];
    const float* Wlg  = (const float*)d_in[11];
    const float* blg  = (const float*)d_in[12];
    const float* Wrg  = (const float*)d_in[13];
    const float* brg  = (const float*)d_in[14];
    const float* Wog  = (const float*)d_in[15];
    const float* bog  = (const float*)d_in[16];

    char* ws = (char*)d_ws;
    u16* Wt = (u16*)ws;
    const size_t off = 256 * 1024;
    const size_t SZ  = (size_t)33554432 * 2;   // 64 MiB per bf16 tensor
    u16* left  = (u16*)(ws + off);
    u16* right = (u16*)(ws + off + SZ);
    u16* og    = (u16*)(ws + off + 2 * SZ);
    u16* om    = (u16*)(ws + off + 3 * SZ);

    hipLaunchKernelGGL(k_prep, dim3(384), dim3(256), 0, stream, Wl, Wlg, Wr, Wrg, Wog, Wo, Wt);
    hipLaunchKernelGGL(k1, dim3(4096), dim3(256), 0, stream,
                       x, ling, linb, Wt, bl, blg, br, brg, bog, left, right, og);
    hipLaunchKernelGGL(k2, dim3(2048), dim3(256), 0, stream, left, right, om);
    hipLaunchKernelGGL(k3, dim3(8, 512), dim3(256), 0, stream, om, og, Wt, loutg, loutb, bo, (float*)d_out);
}

// Round 16
// 250.362 us; speedup vs baseline: 1.0996x; 1.0158x over previous
//
#include <hip/hip_runtime.h>
#include <hip/hip_bf16.h>
#include <cstdint>
#include <cstddef>

typedef unsigned short u16;
typedef short bf16x8 __attribute__((ext_vector_type(8)));
typedef float f32x4 __attribute__((ext_vector_type(4)));

constexpr int Ns = 512;   // N
constexpr int Dd = 128;   // D
constexpr int Cc = 128;   // C
#define EPSV 1e-5f

#define GAS __attribute__((address_space(1)))
#define LAS __attribute__((address_space(3)))

__device__ __forceinline__ u16 f2bf(float f){
    __hip_bfloat16 h = __float2bfloat16(f);
    return *reinterpret_cast<u16*>(&h);
}
__device__ __forceinline__ float bf2f(u16 h){
    return __uint_as_float(((uint32_t)h) << 16);
}
__device__ __forceinline__ float sigmoidf_(float x){
    return __builtin_amdgcn_rcpf(1.0f + __expf(-x));   // rcp: ~1ulp, fine at bf16
}

// ---------------------------------------------------------------------------
// K0: weights -> bf16, transposed [n][k].  Order: Wl,Wlg,Wr,Wrg,Wog,Wo
// ---------------------------------------------------------------------------
__global__ void k_prep(const float* __restrict__ Wl, const float* __restrict__ Wlg,
                       const float* __restrict__ Wr, const float* __restrict__ Wrg,
                       const float* __restrict__ Wog, const float* __restrict__ Wo,
                       u16* __restrict__ Wt){
    int idx = blockIdx.x * 256 + threadIdx.x;
    if (idx >= 6 * 16384) return;
    int m = idx >> 14; int nk = idx & 16383; int n = nk >> 7; int k = nk & 127;
    const float* W = (m == 0) ? Wl : (m == 1) ? Wlg : (m == 2) ? Wr
                   : (m == 3) ? Wrg : (m == 4) ? Wog : Wo;
    Wt[idx] = f2bf(W[k * Cc + n]);
}

// ---------------------------------------------------------------------------
// K1: LN(x) then 5 GEMMs (R8 — measured best: 140 us).  UNCHANGED.
// ---------------------------------------------------------------------------
__global__ __launch_bounds__(256) void k1(
    const float* __restrict__ x, const float* __restrict__ g_ln, const float* __restrict__ b_ln,
    const u16* __restrict__ Wt,
    const float* __restrict__ bl, const float* __restrict__ blg,
    const float* __restrict__ br, const float* __restrict__ brg,
    const float* __restrict__ bog,
    u16* __restrict__ left, u16* __restrict__ right, u16* __restrict__ og)
{
    __shared__ u16  SB[8704];
    __shared__ float gln[128], bln[128];

    const int t   = threadIdx.x;
    const int bid = blockIdx.x;
    const int a0  = (bid >> 6) << 3;
    const int b0  = (bid & 63) << 3;
    const int w = t >> 6, l = t & 63;
    const int lrow = l & 15, g = l >> 4;
    const int nb = w * 32;
    const int orow = g << 2;
    const int kb = a0 >> 3;

    const int r = t >> 2, q = t & 3;
    const int aa = a0 + (r & 7), bb = b0 + (r >> 3);
    const float4* xrow = reinterpret_cast<const float4*>(x + ((size_t)aa * Ns + bb) * Dd);
    float4 xv[8];
#pragma unroll
    for (int i2 = 0; i2 < 8; ++i2) xv[i2] = xrow[q + 4 * i2];
    if (t < 128){ gln[t] = g_ln[t]; bln[t] = b_ln[t]; }

    float s1 = 0.f, s2 = 0.f;
#pragma unroll
    for (int i2 = 0; i2 < 8; ++i2){
        float4 v = xv[i2];
        s1 += v.x + v.y + v.z + v.w;
        s2 += v.x * v.x + v.y * v.y + v.z * v.z + v.w * v.w;
    }
    s1 += __shfl_xor(s1, 1); s1 += __shfl_xor(s1, 2);
    s2 += __shfl_xor(s2, 1); s2 += __shfl_xor(s2, 2);
    const float mm  = s1 * (1.0f / 128.0f);
    const float rsv = rsqrtf(s2 * (1.0f / 128.0f) - mm * mm + EPSV);
    __syncthreads();
#pragma unroll
    for (int i2 = 0; i2 < 8; ++i2){
        const int d = (q + 4 * i2) * 4;
        ushort4 o;
        o.x = f2bf((xv[i2].x - mm) * rsv * gln[d + 0] + bln[d + 0]);
        o.y = f2bf((xv[i2].y - mm) * rsv * gln[d + 1] + bln[d + 1]);
        o.z = f2bf((xv[i2].z - mm) * rsv * gln[d + 2] + bln[d + 2]);
        o.w = f2bf((xv[i2].w - mm) * rsv * gln[d + 3] + bln[d + 3]);
        *reinterpret_cast<ushort4*>(&SB[r * 136 + d]) = o;
    }
    __syncthreads();

    bf16x8 af[4][4];
#pragma unroll
    for (int ks = 0; ks < 4; ++ks)
#pragma unroll
        for (int rf = 0; rf < 4; ++rf)
            af[ks][rf] = *reinterpret_cast<const bf16x8*>(&SB[(rf * 16 + lrow) * 136 + ks * 32 + g * 8]);
    __syncthreads();

    const f32x4 zero4 = {0.f, 0.f, 0.f, 0.f};
    f32x4 aV[4], aG[4];

    auto GEMM1 = [&](const u16* WV, const u16* WG, int cf){
        const int col = nb + cf * 16 + lrow;
#pragma unroll
        for (int rf = 0; rf < 4; ++rf){ aV[rf] = zero4; aG[rf] = zero4; }
#pragma unroll
        for (int ks = 0; ks < 4; ++ks){
            bf16x8 bv = *reinterpret_cast<const bf16x8*>(WV + (size_t)col * 128 + ks * 32 + g * 8);
            bf16x8 bg = *reinterpret_cast<const bf16x8*>(WG + (size_t)col * 128 + ks * 32 + g * 8);
#pragma unroll
            for (int rf = 0; rf < 4; ++rf)
                aV[rf] = __builtin_amdgcn_mfma_f32_16x16x32_bf16(af[ks][rf], bv, aV[rf], 0, 0, 0);
#pragma unroll
            for (int rf = 0; rf < 4; ++rf)
                aG[rf] = __builtin_amdgcn_mfma_f32_16x16x32_bf16(af[ks][rf], bg, aG[rf], 0, 0, 0);
        }
    };
    auto STW = [&](const float* bV, const float* bG, int cf){
        const int col = nb + cf * 16 + lrow;
        const float bVv = bV[col], bGv = bG[col];
#pragma unroll
        for (int rf = 0; rf < 4; ++rf){
            ushort4 pk;
#pragma unroll
            for (int j = 0; j < 4; ++j){
                const float vv = aV[rf][j] + bVv;
                const float gg = aG[rf][j] + bGv;
                ((u16*)&pk)[j] = f2bf(sigmoidf_(gg) * vv);
            }
            *reinterpret_cast<ushort4*>(&SB[col * 68 + rf * 16 + orow]) = pk;
        }
    };
    auto STORE = [&](u16* dst){
#pragma unroll
        for (int it = 0; it < 4; ++it){
            const int cl = it * 32 + (t >> 3);
            const int s  = t & 7;
            int4 v = *reinterpret_cast<const int4*>(&SB[cl * 68 + s * 8]);
            *reinterpret_cast<int4*>(dst + (((size_t)cl * 64 + kb) * Ns + b0) * 8 + s * 8) = v;
        }
    };

    GEMM1(Wt,             Wt + 16384,     0); STW(bl, blg, 0);
    GEMM1(Wt,             Wt + 16384,     1); STW(bl, blg, 1);
    __syncthreads();
    STORE(left);
    __syncthreads();
    GEMM1(Wt + 2 * 16384, Wt + 3 * 16384, 0); STW(br, brg, 0);
    GEMM1(Wt + 2 * 16384, Wt + 3 * 16384, 1); STW(br, brg, 1);
    __syncthreads();
    STORE(right);
    __syncthreads();

    const u16* WO = Wt + (size_t)4 * 16384;
#pragma unroll 1
    for (int cf = 0; cf < 2; ++cf){
        const int col = nb + cf * 16 + lrow;
#pragma unroll
        for (int rf = 0; rf < 4; ++rf) aV[rf] = zero4;
#pragma unroll
        for (int ks = 0; ks < 4; ++ks){
            bf16x8 bv = *reinterpret_cast<const bf16x8*>(WO + (size_t)col * 128 + ks * 32 + g * 8);
#pragma unroll
            for (int rf = 0; rf < 4; ++rf)
                aV[rf] = __builtin_amdgcn_mfma_f32_16x16x32_bf16(af[ks][rf], bv, aV[rf], 0, 0, 0);
        }
        const float bOv = bog[col];
#pragma unroll
        for (int rf = 0; rf < 4; ++rf)
#pragma unroll
            for (int j = 0; j < 4; ++j){
                const int row = rf * 16 + orow + j;
                SB[row * 132 + col] = f2bf(sigmoidf_(aV[rf][j] + bOv));
            }
    }
    __syncthreads();
    const int bsub = t >> 5, c4 = (t & 31) * 4;
#pragma unroll
    for (int a = 0; a < 8; ++a){
        const int row = bsub * 8 + a;
        int2 v = *reinterpret_cast<const int2*>(&SB[row * 132 + c4]);
        *reinterpret_cast<int2*>(og + (((size_t)(a0 + a) * Ns) + (b0 + bsub)) * Cc + c4) = v;
    }
}

// ---------------------------------------------------------------------------
// K2 v2: om[c][i][j] = sum_k left[c][k][i] * right[c][k][j]  (per-channel GEMM)
// m97-style 2-barrier K-loop: per K-step (64 k), stage A/B panel chunks
// (16 KB each) into LDS via global_load_lds width=16 (linear dest = linear
// src, lane-ordered), __syncthreads drain, MFMA from LDS.  Halves L2 read
// traffic (wave pairs now share panels via LDS).  K-order unchanged ->
// bitwise-identical om.  LDS 34.8 KB (sO aliases stage buffer).
// ---------------------------------------------------------------------------
__global__ __launch_bounds__(256) void k2(const u16* __restrict__ left,
                                          const u16* __restrict__ right,
                                          u16* __restrict__ om)
{
    __shared__ u16 ST[17408];          // A: [0,8192) B: [8192,16384); sO alias [0,17408)
    const int bid = blockIdx.x;
    const int xcd = bid & 7, idxx = bid >> 3;
    const int virt = xcd * 256 + idxx;
    const int c    = virt >> 4;
    const int tile = virt & 15;
    const int iy = tile >> 2, jx = tile & 3;
    const int t = threadIdx.x, w = t >> 6, l = t & 63;
    const int wr = w >> 1, wc = w & 1;
    const int ib0 = iy * 128, jb0 = jx * 128;
    const int lrow = l & 15, lkb = l >> 4;
    const u16* Lc = left  + (size_t)c * (Ns * Ns);
    const u16* Rc = right + (size_t)c * (Ns * Ns);
    const f32x4 zero4 = {0.f, 0.f, 0.f, 0.f};
    f32x4 acc[4][4];
#pragma unroll
    for (int rf = 0; rf < 4; ++rf)
#pragma unroll
        for (int cf = 0; cf < 4; ++cf) acc[rf][cf] = zero4;

    // stage K-step s: A chunk = 8 kb x 128 rows x 16B (linear [kbl][row][8])
    auto STAGE = [&](int s){
#pragma unroll
        for (int it = 0; it < 4; ++it){
            const int u = it * 256 + t;            // 1024 units of 16B
            const int kbl = u >> 7, row = u & 127; // uniform kbl per 64-lane span
            const size_t goA = (((size_t)(s * 8 + kbl) * Ns) + ib0 + row) * 8;
            __builtin_amdgcn_global_load_lds(
                (const GAS uint32_t*)(const void*)(Lc + goA),
                (LAS uint32_t*)(void*)&ST[(size_t)u * 8], 16, 0, 0);
        }
#pragma unroll
        for (int it = 0; it < 4; ++it){
            const int u = it * 256 + t;
            const int kbl = u >> 7, row = u & 127;
            const size_t goB = (((size_t)(s * 8 + kbl) * Ns) + jb0 + row) * 8;
            __builtin_amdgcn_global_load_lds(
                (const GAS uint32_t*)(const void*)(Rc + goB),
                (LAS uint32_t*)(void*)&ST[8192 + (size_t)u * 8], 16, 0, 0);
        }
    };

#pragma unroll 1
    for (int s = 0; s < 8; ++s){
        STAGE(s);
        __syncthreads();               // drain vmcnt: stage complete
#pragma unroll
        for (int h = 0; h < 2; ++h){   // two K=32 MFMA substeps (kb order = old ks order)
            const int kbl = h * 4 + lkb;
            bf16x8 af[4], bfr[4];
#pragma unroll
            for (int rf = 0; rf < 4; ++rf)
                af[rf] = *reinterpret_cast<const bf16x8*>(
                    &ST[((size_t)kbl * 128 + wr * 64 + rf * 16 + lrow) * 8]);
#pragma unroll
            for (int cf = 0; cf < 4; ++cf)
                bfr[cf] = *reinterpret_cast<const bf16x8*>(
                    &ST[8192 + ((size_t)kbl * 128 + wc * 64 + cf * 16 + lrow) * 8]);
#pragma unroll
            for (int rf = 0; rf < 4; ++rf)
#pragma unroll
                for (int cf = 0; cf < 4; ++cf)
                    acc[rf][cf] = __builtin_amdgcn_mfma_f32_16x16x32_bf16(af[rf], bfr[cf], acc[rf][cf], 0, 0, 0);
        }
        __syncthreads();               // all reads done before next stage overwrites
    }

    // ---- output: stage in LDS (alias ST), coalesced int4 stores ----
    u16* sO = &ST[0];                  // [128][136]
    const int orow = (l >> 4) << 2;
#pragma unroll
    for (int rf = 0; rf < 4; ++rf)
#pragma unroll
        for (int j2 = 0; j2 < 4; ++j2){
            const int rloc = wr * 64 + rf * 16 + orow + j2;
#pragma unroll
            for (int cf = 0; cf < 4; ++cf)
                sO[rloc * 136 + wc * 64 + cf * 16 + lrow] = f2bf(acc[rf][cf][j2]);
        }
    __syncthreads();
    u16* obase = om + (size_t)c * Ns * Ns + (size_t)ib0 * Ns + jb0;
#pragma unroll
    for (int s = 0; s < 8; ++s){
        const int gg = s * 256 + t;
        const int row = gg >> 4, co = (gg & 15) * 8;
        int4 v = *reinterpret_cast<const int4*>(&sO[row * 136 + co]);
        *reinterpret_cast<int4*>(obase + (size_t)row * Ns + co) = v;
    }
}

// ---------------------------------------------------------------------------
// K3: final = sigmoid(og) * (LN_c(out_mid) @ Wo + bo), fp32 out.  UNCHANGED.
// ---------------------------------------------------------------------------
__global__ __launch_bounds__(256) void k3(
    const u16* __restrict__ om, const u16* __restrict__ og, const u16* __restrict__ Wt,
    const float* __restrict__ g2, const float* __restrict__ b2, const float* __restrict__ bo,
    float* __restrict__ out)
{
    __shared__ char smem[34816];
    u16* X = reinterpret_cast<u16*>(smem);
    u16* O = reinterpret_cast<u16*>(smem) + 8704;
    __shared__ float sg2[128], sb2[128];
    const int i  = blockIdx.y;
    const int j0 = blockIdx.x * 64;
    const int t  = threadIdx.x;
    if (t < 128){ sg2[t] = g2[t]; sb2[t] = b2[t]; }
    {
        const int c = t >> 1, jh = (t & 1) * 32;
        const u16* src = om + (size_t)c * Ns * Ns + (size_t)i * Ns + j0 + jh;
#pragma unroll
        for (int s = 0; s < 8; ++s){
            ushort4 v = reinterpret_cast<const ushort4*>(src)[s];
            const int jj = jh + s * 4;
            X[(jj + 0) * 136 + c] = v.x; X[(jj + 1) * 136 + c] = v.y;
            X[(jj + 2) * 136 + c] = v.z; X[(jj + 3) * 136 + c] = v.w;
        }
    }
    {
        const int jj = t >> 2, qq = t & 3;
        const u16* src = og + ((size_t)i * Ns + j0 + jj) * Cc + qq * 32;
#pragma unroll
        for (int s = 0; s < 4; ++s)
            *reinterpret_cast<int4*>(&O[jj * 136 + qq * 32 + s * 8]) = reinterpret_cast<const int4*>(src)[s];
    }
    __syncthreads();
    const int r = t >> 2, q = t & 3;
    {
        float s1 = 0.f, s2v = 0.f;
#pragma unroll
        for (int e = 0; e < 32; ++e){
            const float v = bf2f(X[r * 136 + q * 32 + e]);
            s1 += v; s2v += v * v;
        }
        s1  += __shfl_xor(s1, 1);  s1  += __shfl_xor(s1, 2);
        s2v += __shfl_xor(s2v, 1); s2v += __shfl_xor(s2v, 2);
        const float mm  = s1 * (1.0f / 128.0f);
        const float rsv = rsqrtf(s2v * (1.0f / 128.0f) - mm * mm + EPSV);
#pragma unroll
        for (int e = 0; e < 32; ++e){
            const int cc = q * 32 + e;
            const float v = bf2f(X[r * 136 + cc]);
            X[r * 136 + cc] = f2bf((v - mm) * rsv * sg2[cc] + sb2[cc]);
        }
    }
    __syncthreads();
    const int w = t >> 6, l = t & 63;
    const int lrow = l & 15, lk = (l >> 4) << 3, nbv = w * 32, orow = (l >> 4) << 2;
    const u16* WO = Wt + (size_t)5 * 16384;
    const f32x4 zero4 = {0.f, 0.f, 0.f, 0.f};
    f32x4 acc[4][2];
#pragma unroll
    for (int rf = 0; rf < 4; ++rf)
#pragma unroll
        for (int cf = 0; cf < 2; ++cf) acc[rf][cf] = zero4;
#pragma unroll
    for (int ks = 0; ks < 4; ++ks){
        const int k0 = ks * 32 + lk;
        bf16x8 af[4];
#pragma unroll
        for (int rf = 0; rf < 4; ++rf)
            af[rf] = *reinterpret_cast<const bf16x8*>(&X[(rf * 16 + lrow) * 136 + k0]);
#pragma unroll
        for (int cf = 0; cf < 2; ++cf){
            bf16x8 bv = *reinterpret_cast<const bf16x8*>(WO + (size_t)(nbv + cf * 16 + lrow) * 128 + k0);
#pragma unroll
            for (int rf = 0; rf < 4; ++rf)
                acc[rf][cf] = __builtin_amdgcn_mfma_f32_16x16x32_bf16(af[rf], bv, acc[rf][cf], 0, 0, 0);
        }
    }
    float gv[2][4][4];
#pragma unroll
    for (int cf = 0; cf < 2; ++cf){
        const int cg = nbv + cf * 16 + lrow;
        const float bov = bo[cg];
#pragma unroll
        for (int rf = 0; rf < 4; ++rf)
#pragma unroll
            for (int j = 0; j < 4; ++j){
                const int row = rf * 16 + orow + j;
                gv[cf][rf][j] = bf2f(O[row * 136 + cg]) * (acc[rf][cf][j] + bov);
            }
    }
    __syncthreads();
    float* sF = reinterpret_cast<float*>(smem);
#pragma unroll
    for (int cf = 0; cf < 2; ++cf){
        const int cg = nbv + cf * 16 + lrow;
#pragma unroll
        for (int rf = 0; rf < 4; ++rf)
#pragma unroll
            for (int j = 0; j < 4; ++j){
                const int row = rf * 16 + orow + j;
                sF[row * 128 + cg] = gv[cf][rf][j];
            }
    }
    __syncthreads();
    const float4* sF4 = reinterpret_cast<const float4*>(smem);
    float* obase = out + ((size_t)i * Ns + j0) * Cc;
#pragma unroll
    for (int s = 0; s < 8; ++s){
        const int gg = s * 256 + t;
        const int row = gg >> 5, co = (gg & 31) * 4;
        float4 v = sF4[gg];
        *reinterpret_cast<float4*>(obase + (size_t)row * Cc + co) = v;
    }
}

// ---------------------------------------------------------------------------
extern "C" void kernel_launch(void* const* d_in, const int* in_sizes, int n_in,
                              void* d_out, int out_size, void* d_ws, size_t ws_size,
                              hipStream_t stream)
{
    const float* x    = (const float*)d_in[0];
    const float* ling = (const float*)d_in[1];
    const float* linb = (const float*)d_in[2];
    const float* loutg= (const float*)d_in[3];
    const float* loutb= (const float*)d_in[4];
    const float* Wl   = (const float*)d_in[5];
    const float* bl   = (const float*)d_in[6];
    const float* Wr   = (const float*)d_in[7];
    const float* br   = (const float*)d_in[8];
    const float* Wo   = (const float*)d_in[9];
    const float* bo   = (const float*)d_in[10];
    const float* Wlg  = (const float*)d_in[11];
    const float* blg  = (const float*)d_in[12];
    const float* Wrg  = (const float*)d_in[13];
    const float* brg  = (const float*)d_in[14];
    const float* Wog  = (const float*)d_in[15];
    const float* bog  = (const float*)d_in[16];

    char* ws = (char*)d_ws;
    u16* Wt = (u16*)ws;
    const size_t off = 256 * 1024;
    const size_t SZ  = (size_t)33554432 * 2;   // 64 MiB per bf16 tensor
    u16* left  = (u16*)(ws + off);
    u16* right = (u16*)(ws + off + SZ);
    u16* og    = (u16*)(ws + off + 2 * SZ);
    u16* om    = (u16*)(ws + off + 3 * SZ);

    hipLaunchKernelGGL(k_prep, dim3(384), dim3(256), 0, stream, Wl, Wlg, Wr, Wrg, Wog, Wo, Wt);
    hipLaunchKernelGGL(k1, dim3(4096), dim3(256), 0, stream,
                       x, ling, linb, Wt, bl, blg, br, brg, bog, left, right, og);
    hipLaunchKernelGGL(k2, dim3(2048), dim3(256), 0, stream, left, right, om);
    hipLaunchKernelGGL(k3, dim3(8, 512), dim3(256), 0, stream, om, og, Wt, loutg, loutb, bo, (float*)d_out);
}